// Round 10
// baseline (498.498 us; speedup 1.0000x reference)
//
#include <hip/hip_runtime.h>

#define N_NODES 100000
#define N_EDGES 1600000
#define D 64
#define N_GRAPHS 64
#define NBLK ((N_NODES + 255) / 256)   // 391 scan blocks
#define WTS 68                         // WT row stride (floats): conflict-free
#define NBUF 128                       // staged csr entries per row (fast path)

// ---------------- init: deg=1 (self loop), cnt=0, out=0 ----------------
__global__ void k_init(float* __restrict__ deg, int* __restrict__ cnt,
                       float* __restrict__ out) {
    int i = blockIdx.x * blockDim.x + threadIdx.x;
    if (i < N_NODES) { deg[i] = 1.0f; cnt[i] = 0; }
    if (i < N_GRAPHS * D) out[i] = 0.0f;
}

// ---------------- degree + in-edge count ----------------
__global__ void k_count_deg(const int* __restrict__ dst, const float* __restrict__ ew,
                            float* __restrict__ deg, int* __restrict__ cnt) {
    int e = blockIdx.x * blockDim.x + threadIdx.x;
    if (e < N_EDGES) {
        int d = dst[e];
        atomicAdd(&deg[d], ew[e]);
        atomicAdd(&cnt[d], 1);
    }
}

// ---------------- dinv (fused) + exclusive scan of cnt -> rowptr ------------
__global__ void k_scan1(const int* __restrict__ cnt, int* __restrict__ partial,
                        int* __restrict__ bsums, float* __restrict__ deg) {
    int t = threadIdx.x, b = blockIdx.x, i = b * 256 + t;
    if (i < N_NODES) {            // fused dinv: deg -> rsqrt(deg)
        float d = deg[i];
        deg[i] = d > 0.f ? rsqrtf(d) : 0.f;
    }
    int v = (i < N_NODES) ? cnt[i] : 0;
    int incl = v;
    int lane = t & 63;
#pragma unroll
    for (int off = 1; off < 64; off <<= 1) {
        int u = __shfl_up(incl, off);
        if (lane >= off) incl += u;
    }
    __shared__ int wsum[4];
    int w = t >> 6;
    if (lane == 63) wsum[w] = incl;
    __syncthreads();
    int add = 0;
    for (int k = 0; k < w; ++k) add += wsum[k];
    incl += add;
    if (i < N_NODES) partial[i] = incl;
    if (t == 255) bsums[b] = incl;
}

__global__ void k_scan2(int* __restrict__ bsums) {
    __shared__ int s[512];
    int t = threadIdx.x;
    s[t] = (t < NBLK) ? bsums[t] : 0;
    __syncthreads();
    for (int off = 1; off < 512; off <<= 1) {
        int u = (t >= off) ? s[t - off] : 0;
        __syncthreads();
        s[t] += u;
        __syncthreads();
    }
    if (t < NBLK) bsums[t] = (t == 0) ? 0 : s[t - 1];  // exclusive
}

__global__ void k_scan3(const int* __restrict__ partial, const int* __restrict__ cnt,
                        const int* __restrict__ bsums, int* __restrict__ rowptr,
                        int* __restrict__ cursor) {
    int i = blockIdx.x * 256 + threadIdx.x;
    if (i < N_NODES) {
        int excl = partial[i] - cnt[i] + bsums[blockIdx.x];
        rowptr[i] = excl;
        cursor[i] = excl;
    }
}

// ---------------- scatter edges into CSR (src, norm) grouped by dst ----------
__global__ void k_scatter(const int* __restrict__ src, const int* __restrict__ dst,
                          const float* __restrict__ ew, const float* __restrict__ dinv,
                          int* __restrict__ cursor, float2* __restrict__ csr) {
    int e = blockIdx.x * blockDim.x + threadIdx.x;
    if (e < N_EDGES) {
        int s = src[e];
        int d = dst[e];
        float nrm = dinv[s] * ew[e] * dinv[d];
        int pos = atomicAdd(&cursor[d], 1);
        csr[pos] = make_float2(__int_as_float(s), nrm);
    }
}

// ---------------- fused layer ----------------
// One row per wave-iteration, CSR stream pipelined through LDS (T14 split):
//   top of iter i : issue coalesced per-lane loads of row(i+1)'s csr (regs)
//   middle        : process row(i) reading csr entries from LDS (ds_read_b64
//                   broadcast, ~6cy) -> 16 independent gathers, ONE memory
//                   latency per row on the critical path
//   after process : ds_write the register-held entries into the other buffer
//                   (their ~600cy global latency fully hidden under process)
// GEMM: lane's W-column from transposed-W LDS (stride 68, conflict-free),
// acc broadcast via 1 ds_write + same-address float4 reads.
// LAYER==1: write relu(.)  LAYER==2: pool-atomicAdd relu(.) into out[batch].
template <int LAYER>
__global__ __launch_bounds__(256) void k_layer(
        const float* __restrict__ in, const float* __restrict__ W,
        const float* __restrict__ bias, const float* __restrict__ dinv,
        const int* __restrict__ rowptr, const int* __restrict__ cnt,
        const float2* __restrict__ csr, const int* __restrict__ batch,
        float* __restrict__ outp) {
    __shared__ float  WTs[D * WTS];        // 17408 B transposed W
    __shared__ float  aw[4][D];            // 1 KB per-wave row staging
    __shared__ float2 ebuf[4][2][NBUF];    // 8 KB per-wave csr double-buffer
    __shared__ float  bs[D];

    {   // stage W transposed: WTs[c*WTS + k] = W[k*D + c]
        int t = threadIdx.x;
#pragma unroll
        for (int i = 0; i < 16; ++i) {
            int idx = t + i * 256;
            int k = idx >> 6, c = idx & 63;
            WTs[c * WTS + k] = W[idx];
        }
        if (t < D) bs[t] = bias[t];
    }
    __syncthreads();

    const int lane = threadIdx.x & 63;
    const int wid  = threadIdx.x >> 6;
    float*  awm = aw[wid];
    float2 (*eb)[NBUF] = ebuf[wid];
    const float bl = bs[lane];

    int gw = (blockIdx.x * blockDim.x + threadIdx.x) >> 6;
    const int tw = (gridDim.x * blockDim.x) >> 6;

    int row = gw;
    int st = 0, dg = 0, cur = 0;

    if (row < N_NODES) {   // prologue: stage row's csr into buffer 0
        st = __builtin_amdgcn_readfirstlane(rowptr[row]);
        dg = __builtin_amdgcn_readfirstlane(cnt[row]);
        int ne = dg < NBUF ? dg : NBUF;
        float2 mA, mB;
        if (lane < ne)      mA = csr[st + lane];
        if (64 + lane < ne) mB = csr[st + 64 + lane];
        if (lane < ne)      eb[0][lane] = mA;
        if (64 + lane < ne) eb[0][64 + lane] = mB;
    }

    for (; row < N_NODES; row += tw) {
        const int nrow = row + tw;
        int stn = 0, dgn = 0, nen = 0;
        float2 mA = make_float2(0.f, 0.f), mB = make_float2(0.f, 0.f);
        if (nrow < N_NODES) {   // issue next row's csr loads EARLY (regs)
            stn = __builtin_amdgcn_readfirstlane(rowptr[nrow]);
            dgn = __builtin_amdgcn_readfirstlane(cnt[nrow]);
            nen = dgn < NBUF ? dgn : NBUF;
            if (lane < nen)      mA = csr[stn + lane];
            if (64 + lane < nen) mB = csr[stn + 64 + lane];
        }

        // ---- process current row from LDS-staged csr ----
        float di = dinv[row];
        float acc = in[row * D + lane] * (di * di);   // self-loop
        const float2* ebf = eb[cur];
        const int ne = dg < NBUF ? dg : NBUF;
        const int passes = (ne + 7) >> 3;
        for (int p = 0; p < passes; ++p) {
            const int j = p * 8;
            // 8 broadcast LDS reads (cheap), then 8 independent gathers
            float2 e0 = ebf[(j + 0 < ne) ? j + 0 : 0];
            float2 e1 = ebf[(j + 1 < ne) ? j + 1 : 0];
            float2 e2 = ebf[(j + 2 < ne) ? j + 2 : 0];
            float2 e3 = ebf[(j + 3 < ne) ? j + 3 : 0];
            float2 e4 = ebf[(j + 4 < ne) ? j + 4 : 0];
            float2 e5 = ebf[(j + 5 < ne) ? j + 5 : 0];
            float2 e6 = ebf[(j + 6 < ne) ? j + 6 : 0];
            float2 e7 = ebf[(j + 7 < ne) ? j + 7 : 0];
            float w0 = (j + 0 < ne) ? e0.y : 0.f;
            float w1 = (j + 1 < ne) ? e1.y : 0.f;
            float w2 = (j + 2 < ne) ? e2.y : 0.f;
            float w3 = (j + 3 < ne) ? e3.y : 0.f;
            float w4 = (j + 4 < ne) ? e4.y : 0.f;
            float w5 = (j + 5 < ne) ? e5.y : 0.f;
            float w6 = (j + 6 < ne) ? e6.y : 0.f;
            float w7 = (j + 7 < ne) ? e7.y : 0.f;
            int s0 = __builtin_amdgcn_readfirstlane(__float_as_int(e0.x));
            int s1 = __builtin_amdgcn_readfirstlane(__float_as_int(e1.x));
            int s2 = __builtin_amdgcn_readfirstlane(__float_as_int(e2.x));
            int s3 = __builtin_amdgcn_readfirstlane(__float_as_int(e3.x));
            int s4 = __builtin_amdgcn_readfirstlane(__float_as_int(e4.x));
            int s5 = __builtin_amdgcn_readfirstlane(__float_as_int(e5.x));
            int s6 = __builtin_amdgcn_readfirstlane(__float_as_int(e6.x));
            int s7 = __builtin_amdgcn_readfirstlane(__float_as_int(e7.x));
            float v0 = in[s0 * D + lane];
            float v1 = in[s1 * D + lane];
            float v2 = in[s2 * D + lane];
            float v3 = in[s3 * D + lane];
            float v4 = in[s4 * D + lane];
            float v5 = in[s5 * D + lane];
            float v6 = in[s6 * D + lane];
            float v7 = in[s7 * D + lane];
            acc = fmaf(v0, w0, acc);
            acc = fmaf(v1, w1, acc);
            acc = fmaf(v2, w2, acc);
            acc = fmaf(v3, w3, acc);
            acc = fmaf(v4, w4, acc);
            acc = fmaf(v5, w5, acc);
            acc = fmaf(v6, w6, acc);
            acc = fmaf(v7, w7, acc);
        }
        // rare tail (dg > NBUF): direct uniform loads, correctness only
        for (int j = NBUF; j < dg; ++j) {
            float2 e = csr[st + j];
            int s = __builtin_amdgcn_readfirstlane(__float_as_int(e.x));
            acc = fmaf(in[s * D + lane], e.y, acc);
        }

        // ---- write next row's csr into the other buffer (loads now retired) -
        {
            float2* ebn = eb[cur ^ 1];
            if (lane < nen)      ebn[lane] = mA;
            if (64 + lane < nen) ebn[64 + lane] = mB;
        }

        // ---- GEMM: r[lane] = sum_k acc[k] * W[k][lane] ----
        awm[lane] = acc;   // same-wave LDS RAW; compiler inserts lgkmcnt wait
        float r0 = 0.f, r1 = 0.f, r2 = 0.f, r3 = 0.f;
#pragma unroll
        for (int t = 0; t < 16; ++t) {
            float4 a = *(const float4*)&awm[t * 4];                // broadcast
            float4 w = *(const float4*)&WTs[lane * WTS + t * 4];   // conflict-free
            r0 = fmaf(a.x, w.x, r0);
            r1 = fmaf(a.y, w.y, r1);
            r2 = fmaf(a.z, w.z, r2);
            r3 = fmaf(a.w, w.w, r3);
        }
        float r = fmaxf((r0 + r1) + (r2 + r3) + bl, 0.f);

        if (LAYER == 1) {
            outp[row * D + lane] = r;
        } else {
            atomicAdd(&outp[batch[row] * D + lane], r);
        }

        st = stn; dg = dgn; cur ^= 1;
    }
}

// ---------------- finalize pool: divide by per-graph node count ----------------
__global__ void k_finalize(float* __restrict__ out, const int* __restrict__ batch) {
    int g = blockIdx.x;
    int lane = threadIdx.x;
    int lo = 0, hi = N_NODES;
    while (lo < hi) { int m = (lo + hi) >> 1; if (batch[m] < g) lo = m + 1; else hi = m; }
    int start = lo;
    hi = N_NODES;
    while (lo < hi) { int m = (lo + hi) >> 1; if (batch[m] < g + 1) lo = m + 1; else hi = m; }
    float c = (float)(lo - start);
    out[g * D + lane] /= fmaxf(c, 1.0f);
}

// ---------------- launch ----------------
extern "C" void kernel_launch(void* const* d_in, const int* in_sizes, int n_in,
                              void* d_out, int out_size, void* d_ws, size_t ws_size,
                              hipStream_t stream) {
    const float* x     = (const float*)d_in[0];
    const int*   ei    = (const int*)d_in[1];
    const int*   src   = ei;
    const int*   dst   = ei + N_EDGES;
    const int*   batch = (const int*)d_in[2];
    const float* ew    = (const float*)d_in[3];
    const float* W1    = (const float*)d_in[4];
    const float* b1    = (const float*)d_in[5];
    const float* W2    = (const float*)d_in[6];
    const float* b2    = (const float*)d_in[7];
    float* out = (float*)d_out;

    char* ws = (char*)d_ws;
    float*  bufA   = (float*)(ws);                    // 25.6 MB  h1
    float2* csr    = (float2*)(ws + 25600000);        // 12.8 MB  (src, norm)
    float*  deg    = (float*)(ws + 38400000);         // 400 KB   deg -> dinv
    int*    cnt    = (int*)(ws + 38800000);           // 400 KB
    int*    rowptr = (int*)(ws + 39200000);           // 400 KB
    int*    cursor = (int*)(ws + 39600000);           // 400 KB
    int*    bsums  = (int*)(ws + 40000000);           // 2 KB

    // normalization + CSR build
    k_init<<<NBLK, 256, 0, stream>>>(deg, cnt, out);
    k_count_deg<<<(N_EDGES + 255) / 256, 256, 0, stream>>>(dst, ew, deg, cnt);
    k_scan1<<<NBLK, 256, 0, stream>>>(cnt, rowptr, bsums, deg);   // + fused dinv
    k_scan2<<<1, 512, 0, stream>>>(bsums);
    k_scan3<<<NBLK, 256, 0, stream>>>(rowptr, cnt, bsums, rowptr, cursor);
    k_scatter<<<(N_EDGES + 255) / 256, 256, 0, stream>>>(src, dst, ew, deg, cursor, csr);

    // layer 1: bufA = relu((A x) W1 + b1)
    k_layer<1><<<2048, 256, 0, stream>>>(x, W1, b1, deg, rowptr, cnt, csr, batch, bufA);
    // layer 2 + pool-sum: out[g] += relu((A bufA) W2 + b2)
    k_layer<2><<<2048, 256, 0, stream>>>(bufA, W2, b2, deg, rowptr, cnt, csr, batch, out);
    // mean
    k_finalize<<<N_GRAPHS, D, 0, stream>>>(out, batch);
}